// Round 2
// baseline (180.049 us; speedup 1.0000x reference)
//
#include <hip/hip_runtime.h>

// Problem constants (from reference setup_inputs): x (32,256,56,56) f32,
// cols (64,4) i32 = arange(256). Per (b,g,w,h): among the 4 channels
// cols[g,:], keep only the first-max, zero others, then ReLU.
constexpr int B  = 32;
constexpr int C  = 256;
constexpr int W  = 56;
constexpr int H  = 56;
constexpr int G  = 64;
constexpr int GS = 4;
constexpr int P  = W * H;       // 3136 spatial elems per channel (contiguous)
constexpr int P4 = P / 4;       // 784 float4 units per channel (16B aligned)
constexpr int TOTAL = B * G * P4;   // 1,605,632 threads
constexpr int BLOCK = 256;

__global__ __launch_bounds__(BLOCK) void cgm_kernel(const float* __restrict__ x,
                                                    const int* __restrict__ cols,
                                                    float* __restrict__ out) {
    int tid = blockIdx.x * BLOCK + threadIdx.x;
    if (tid >= TOTAL) return;

    int p4 = tid % P4;          // which float4 within the spatial plane
    int bg = tid / P4;
    int g  = bg % G;
    int b  = bg / G;

    long base_p = (long)p4 * 4;

    // Channel offsets for the 4 group slots (wave-uniform cols read, broadcast).
    long off[GS];
#pragma unroll
    for (int s = 0; s < GS; ++s) {
        int c = cols[g * GS + s];
        off[s] = ((long)b * C + c) * P + base_p;
    }

    // 4 coalesced float4 loads (one per group slot; spatially contiguous).
    float vv[GS][4];
#pragma unroll
    for (int s = 0; s < GS; ++s) {
        float4 v = *reinterpret_cast<const float4*>(x + off[s]);
        vv[s][0] = v.x; vv[s][1] = v.y; vv[s][2] = v.z; vv[s][3] = v.w;
    }

    float oo[GS][4];
#pragma unroll
    for (int s = 0; s < GS; ++s)
#pragma unroll
        for (int j = 0; j < 4; ++j) oo[s][j] = 0.0f;

    // Component-wise argmax with FIRST-max tie-break (strict > update),
    // matching jnp.argmax, then ReLU on the surviving value.
#pragma unroll
    for (int j = 0; j < 4; ++j) {
        int   bi   = 0;
        float best = vv[0][j];
#pragma unroll
        for (int s = 1; s < GS; ++s) {
            if (vv[s][j] > best) { best = vv[s][j]; bi = s; }
        }
        float r = best > 0.0f ? best : 0.0f;
        // scatter into the winner's slot (bi is per-component)
#pragma unroll
        for (int s = 0; s < GS; ++s) {
            if (s == bi) oo[s][j] = r;
        }
    }

    // 4 coalesced float4 stores.
#pragma unroll
    for (int s = 0; s < GS; ++s) {
        float4 o;
        o.x = oo[s][0]; o.y = oo[s][1]; o.z = oo[s][2]; o.w = oo[s][3];
        *reinterpret_cast<float4*>(out + off[s]) = o;
    }
}

extern "C" void kernel_launch(void* const* d_in, const int* in_sizes, int n_in,
                              void* d_out, int out_size, void* d_ws, size_t ws_size,
                              hipStream_t stream) {
    const float* x    = (const float*)d_in[0];
    const int*   cols = (const int*)d_in[1];
    float*       out  = (float*)d_out;

    int blocks = (TOTAL + BLOCK - 1) / BLOCK;
    cgm_kernel<<<dim3(blocks), dim3(BLOCK), 0, stream>>>(x, cols, out);
}